// Round 3
// baseline (93.622 us; speedup 1.0000x reference)
//
#include <hip/hip_runtime.h>

#define NW   10
#define QDIM 1024
#define SBUF 1160   // padded float2 slots per state (max P2i(1023)=1149)

// CNOT-ring fused permutation: psi_final[i] = psi_in[gperm(i)].
// Linear over GF(2) (composition of linear maps), so gperm(a^b)=gperm(a)^gperm(b).
__device__ __forceinline__ int gperm(int v) {
    #pragma unroll
    for (int k = 9; k >= 0; --k) {
        const int cs = 9 - k;                 // control bit (qubit k)
        const int ts = 9 - ((k + 1) % NW);    // target bit (qubit (k+1)%10)
        v ^= ((v >> cs) & 1) << ts;
    }
    return v;
}

// Padded physical index (float2 units): +2 slots per 16 keeps 16B alignment
// for even i and breaks power-of-2 bank strides.
__device__ __forceinline__ int P2i(int i) { return i + ((i >> 4) << 1); }

// Complex gate [[a,b],[-conj(b),conj(a)]] on pairs (r, r+2^SH), 32 amps.
template<int SH>
__device__ __forceinline__ void cg32(float* re, float* im,
                                     float ar, float ai, float br, float bi) {
    #pragma unroll
    for (int base = 0; base < 32; base += (2 << SH)) {
        #pragma unroll
        for (int off = 0; off < (1 << SH); ++off) {
            const int r0 = base + off, r1 = r0 + (1 << SH);
            const float v0r = re[r0], v0i = im[r0];
            const float v1r = re[r1], v1i = im[r1];
            re[r0] =  ar * v0r - ai * v0i + br * v1r - bi * v1i;
            im[r0] =  ar * v0i + ai * v0r + br * v1i + bi * v1r;
            re[r1] = -br * v0r - bi * v0i + ar * v1r + ai * v1i;
            im[r1] =  bi * v0r - br * v0i + ar * v1i - ai * v1r;
        }
    }
}

// Real RY gate [[c,-s],[s,c]] on pairs (r, r+2^SH), 32 amps.
template<int SH>
__device__ __forceinline__ void rg32(float* re, float* im, float c, float s) {
    #pragma unroll
    for (int base = 0; base < 32; base += (2 << SH)) {
        #pragma unroll
        for (int off = 0; off < (1 << SH); ++off) {
            const int r0 = base + off, r1 = r0 + (1 << SH);
            const float v0r = re[r0], v0i = im[r0];
            const float v1r = re[r1], v1i = im[r1];
            re[r0] = c * v0r - s * v1r;  im[r0] = c * v0i - s * v1i;
            re[r1] = s * v0r + c * v1r;  im[r1] = s * v0i + c * v1i;
        }
    }
}

// Pre-kernel: gate coefficients (uniform across states) -> d_ws.
__global__ void qsa_coef(const float* __restrict__ rx0,
                         const float* __restrict__ ry0,
                         const float* __restrict__ ry1,
                         float* __restrict__ cf) {
    const int j = threadIdx.x;
    if (j < NW) {
        float sx, cx, sy0, cy0, sy1, cy1;
        sincosf(0.5f * rx0[j], &sx,  &cx);
        sincosf(0.5f * ry0[j], &sy0, &cy0);
        sincosf(0.5f * ry1[j], &sy1, &cy1);
        cf[4 * j + 0] =  cy0 * cx;   // ar   (fused RY(ry0)*RX(rx0))
        cf[4 * j + 1] =  sy0 * sx;   // ai
        cf[4 * j + 2] = -sy0 * cx;   // br
        cf[4 * j + 3] = -cy0 * sx;   // bi
        cf[40 + 2 * j]     = cy1;
        cf[40 + 2 * j + 1] = sy1;
    }
}

// Main: 1 wave per block, 2 states per wave (32 threads/state),
// 32 amps/thread (5 owned bits). 3 LDS trips total:
//   L0: i = s<<5 | r  (owned bits 0-4 -> wires 9..5)
//   L1: i = r<<5 | s  (owned bits 5-9 -> wires 4..0)
//   T1: L0->L1;  T2: L1 -> CNOT-gather -> L0;  T3: L0->L1.
__global__ __launch_bounds__(64) void qsa_main(
    const float* __restrict__ x,
    const float* __restrict__ cf,
    float* __restrict__ out) {

    __shared__ __align__(16) float2 sp[2 * SBUF];

    const int t   = threadIdx.x;
    const int s   = t & 31;          // lane within state
    const int sub = t >> 5;          // which of the 2 states
    const int n   = (blockIdx.x << 1) | sub;
    float2* mysp  = sp + sub * SBUF;

    // Uniform coefficients (scalar loads -> SGPRs)
    float g1[40], g2[20];
    #pragma unroll
    for (int k = 0; k < 40; ++k) g1[k] = cf[k];
    #pragma unroll
    for (int k = 0; k < 20; ++k) g2[k] = cf[40 + k];

    // ---- load 32 contiguous floats of row n, sum of squares ----
    float re[32], im[32];
    const float* xr = x + ((size_t)n << 10) + (s << 5);
    float ss = 0.f;
    #pragma unroll
    for (int r = 0; r < 32; r += 4) {
        const float4 v = *reinterpret_cast<const float4*>(xr + r);
        re[r] = v.x; re[r + 1] = v.y; re[r + 2] = v.z; re[r + 3] = v.w;
        ss += v.x * v.x + v.y * v.y + v.z * v.z + v.w * v.w;
    }
    #pragma unroll
    for (int b = 16; b > 0; b >>= 1) ss += __shfl_xor(ss, b, 64);
    const float scale = 1.0f / fmaxf(sqrtf(ss), 1e-12f);

    // ================= layer 1, phase A (L0: wires 9,8,7,6,5) =============
    {   // wire 9 (SH=0): input real, fold in normalization
        const float ar = g1[36], ai = g1[37], br = g1[38], bi = g1[39];
        #pragma unroll
        for (int r = 0; r < 32; r += 2) {
            const float v0 = re[r] * scale, v1 = re[r + 1] * scale;
            re[r]     =  ar * v0 + br * v1;  im[r]     = ai * v0 + bi * v1;
            re[r + 1] = -br * v0 + ar * v1;  im[r + 1] = bi * v0 - ai * v1;
        }
    }
    cg32<1>(re, im, g1[32], g1[33], g1[34], g1[35]);   // wire 8
    cg32<2>(re, im, g1[28], g1[29], g1[30], g1[31]);   // wire 7
    cg32<3>(re, im, g1[24], g1[25], g1[26], g1[27]);   // wire 6
    cg32<4>(re, im, g1[20], g1[21], g1[22], g1[23]);   // wire 5

    // T1: write L0-contiguous (b128), read L1-strided (b64, lane-contiguous)
    #pragma unroll
    for (int r = 0; r < 32; r += 2)
        *reinterpret_cast<float4*>(&mysp[P2i((s << 5) | r)]) =
            make_float4(re[r], im[r], re[r + 1], im[r + 1]);
    __syncthreads();
    #pragma unroll
    for (int r = 0; r < 32; ++r) {
        const float2 v = mysp[P2i((r << 5) | s)];
        re[r] = v.x; im[r] = v.y;
    }

    // ================= layer 1, phase B (L1: wires 4,3,2,1,0) =============
    cg32<0>(re, im, g1[16], g1[17], g1[18], g1[19]);   // wire 4
    cg32<1>(re, im, g1[12], g1[13], g1[14], g1[15]);   // wire 3
    cg32<2>(re, im, g1[ 8], g1[ 9], g1[10], g1[11]);   // wire 2
    cg32<3>(re, im, g1[ 4], g1[ 5], g1[ 6], g1[ 7]);   // wire 1
    cg32<4>(re, im, g1[ 0], g1[ 1], g1[ 2], g1[ 3]);   // wire 0

    // T2: write L1-strided, read CNOT-gather landing in L0 layout
    __syncthreads();
    #pragma unroll
    for (int r = 0; r < 32; ++r)
        mysp[P2i((r << 5) | s)] = make_float2(re[r], im[r]);
    __syncthreads();
    {
        const int gt = gperm(s << 5);
        #pragma unroll
        for (int r = 0; r < 32; ++r) {
            const float2 v = mysp[P2i(gt ^ gperm(r))];  // gperm(r) const-folds
            re[r] = v.x; im[r] = v.y;
        }
    }

    // ================= layer 2, phase A2 (L0: wires 9..5) =================
    rg32<0>(re, im, g2[18], g2[19]);   // wire 9
    rg32<1>(re, im, g2[16], g2[17]);   // wire 8
    rg32<2>(re, im, g2[14], g2[15]);   // wire 7
    rg32<3>(re, im, g2[12], g2[13]);   // wire 6
    rg32<4>(re, im, g2[10], g2[11]);   // wire 5

    // T3: write L0-contiguous (b128), read L1-strided
    __syncthreads();
    #pragma unroll
    for (int r = 0; r < 32; r += 2)
        *reinterpret_cast<float4*>(&mysp[P2i((s << 5) | r)]) =
            make_float4(re[r], im[r], re[r + 1], im[r + 1]);
    __syncthreads();
    #pragma unroll
    for (int r = 0; r < 32; ++r) {
        const float2 v = mysp[P2i((r << 5) | s)];
        re[r] = v.x; im[r] = v.y;
    }

    // ================= layer 2, phase B2 (L1: wires 4..0) =================
    rg32<0>(re, im, g2[ 8], g2[ 9]);   // wire 4
    rg32<1>(re, im, g2[ 6], g2[ 7]);   // wire 3
    rg32<2>(re, im, g2[ 4], g2[ 5]);   // wire 2
    rg32<3>(re, im, g2[ 2], g2[ 3]);   // wire 1
    rg32<4>(re, im, g2[ 0], g2[ 1]);   // wire 0

    // ---- Z expectations in L1 layout: i = r<<5 | s ----
    // wires 0..4 <- i bits 9..5 = r bits 4..0 (compile-time signs)
    // wires 5..9 <- i bits 4..0 = s bits      (Walsh transform over lanes)
    float P = 0.f, a0 = 0.f, a1 = 0.f, a2 = 0.f, a3 = 0.f, a4 = 0.f;
    #pragma unroll
    for (int r = 0; r < 32; ++r) {
        const float p = re[r] * re[r] + im[r] * im[r];
        P  += p;
        a0 += (r & 16) ? -p : p;   // wire 0
        a1 += (r &  8) ? -p : p;   // wire 1
        a2 += (r &  4) ? -p : p;   // wire 2
        a3 += (r &  2) ? -p : p;   // wire 3
        a4 += (r &  1) ? -p : p;   // wire 4
    }
    #pragma unroll
    for (int b = 1; b < 32; b <<= 1) {
        a0 += __shfl_xor(a0, b, 64);
        a1 += __shfl_xor(a1, b, 64);
        a2 += __shfl_xor(a2, b, 64);
        a3 += __shfl_xor(a3, b, 64);
        a4 += __shfl_xor(a4, b, 64);
        const float e = __shfl_xor(P, b, 64);
        P = (s & b) ? (e - P) : (e + P);   // fast WHT: lane m -> W(m)
    }
    float* o = out + (size_t)n * NW;
    if (s == 0) { o[0] = a0; o[1] = a1; o[2] = a2; o[3] = a3; o[4] = a4; }
    if (s == 1)  o[9] = P;   // wire 9 <- W(1)
    if (s == 2)  o[8] = P;   // wire 8 <- W(2)
    if (s == 4)  o[7] = P;   // wire 7 <- W(4)
    if (s == 8)  o[6] = P;   // wire 6 <- W(8)
    if (s == 16) o[5] = P;   // wire 5 <- W(16)
}

extern "C" void kernel_launch(void* const* d_in, const int* in_sizes, int n_in,
                              void* d_out, int out_size, void* d_ws, size_t ws_size,
                              hipStream_t stream) {
    const float* x   = (const float*)d_in[0];
    const float* rx0 = (const float*)d_in[1];
    const float* ry0 = (const float*)d_in[2];
    const float* ry1 = (const float*)d_in[3];
    float* out = (float*)d_out;
    float* cf  = (float*)d_ws;                // 60 floats
    const int nstates = in_sizes[0] / QDIM;   // 4096

    qsa_coef<<<1, 64, 0, stream>>>(rx0, ry0, ry1, cf);
    qsa_main<<<nstates / 2, 64, 0, stream>>>(x, cf, out);
}

// Round 4
// 82.346 us; speedup vs baseline: 1.1369x; 1.1369x over previous
//
#include <hip/hip_runtime.h>

#define NW 10

// CNOT-ring fused permutation: psi_final[i] = psi_in[gperm(i)].
// Linear over GF(2), so gperm(a^b) = gperm(a)^gperm(b).
__device__ __forceinline__ int gperm(int v) {
    #pragma unroll
    for (int k = 9; k >= 0; --k) {
        const int cs = 9 - k;                 // control bit (qubit k)
        const int ts = 9 - ((k + 1) % NW);    // target bit (qubit (k+1)%10)
        v ^= ((v >> cs) & 1) << ts;
    }
    return v;
}

// Two-level padded physical index (float units).
// Proven patterns: L0/L2 vector trips uniform over 32 banks; L1 scalar trips
// 2-way (free, m136); 16B alignment preserved (all pad terms %4==0).
__device__ __forceinline__ int PF(int i) {
    return i + ((i >> 5) << 2) + ((i >> 8) << 3);
}
#define PBUF 1176   // max PF(1023) = 1171

// Complex gate [[a,b],[-conj(b),conj(a)]] on register pairs (r, r+2^SH).
template<int SH>
__device__ __forceinline__ void cg(float* re, float* im,
                                   float ar, float ai, float br, float bi) {
    #pragma unroll
    for (int base = 0; base < 16; base += (2 << SH)) {
        #pragma unroll
        for (int off = 0; off < (1 << SH); ++off) {
            const int r0 = base + off, r1 = r0 + (1 << SH);
            const float v0r = re[r0], v0i = im[r0];
            const float v1r = re[r1], v1i = im[r1];
            re[r0] =  ar * v0r - ai * v0i + br * v1r - bi * v1i;
            im[r0] =  ar * v0i + ai * v0r + br * v1i + bi * v1r;
            re[r1] = -br * v0r - bi * v0i + ar * v1r + ai * v1i;
            im[r1] =  bi * v0r - br * v0i + ar * v1i - ai * v1r;
        }
    }
}

// Real RY gate [[c,-s],[s,c]] on register pairs (r, r+2^SH).
template<int SH>
__device__ __forceinline__ void rg(float* re, float* im, float c, float s) {
    #pragma unroll
    for (int base = 0; base < 16; base += (2 << SH)) {
        #pragma unroll
        for (int off = 0; off < (1 << SH); ++off) {
            const int r0 = base + off, r1 = r0 + (1 << SH);
            const float v0r = re[r0], v0i = im[r0];
            const float v1r = re[r1], v1i = im[r1];
            re[r0] = c * v0r - s * v1r;  im[r0] = c * v0i - s * v1i;
            re[r1] = s * v0r + c * v1r;  im[r1] = s * v0i + c * v1i;
        }
    }
}

// One wave (64 threads) per block = per state. 16 amps/lane.
// Layouts: L0: i = t<<4 | r;  L1: i = (t>>4)<<8 | r<<4 | (t&15);
//          L2: i = ((r>>2)&3)<<8 | t<<2 | (r&3).
__global__ __launch_bounds__(64) void qsa_main(
    const float* __restrict__ x,
    const float* __restrict__ rx0,
    const float* __restrict__ ry0,
    const float* __restrict__ ry1,
    float* __restrict__ out) {

    __shared__ __align__(16) float reb[PBUF];
    __shared__ __align__(16) float imb[PBUF];
    __shared__ float cf[64];   // [4j..4j+3]=fused RY*RX wire j; [40+2j..]=RY(ry1)

    const int t = threadIdx.x;
    const int n = blockIdx.x;

    // ---- per-wave gate coefficients (lanes 0..9) ----
    if (t < NW) {
        float sx, cx, sy0, cy0, sy1, cy1;
        sincosf(0.5f * rx0[t], &sx,  &cx);
        sincosf(0.5f * ry0[t], &sy0, &cy0);
        sincosf(0.5f * ry1[t], &sy1, &cy1);
        cf[4 * t + 0] =  cy0 * cx;   // ar
        cf[4 * t + 1] =  sy0 * sx;   // ai
        cf[4 * t + 2] = -sy0 * cx;   // br
        cf[4 * t + 3] = -cy0 * sx;   // bi
        cf[40 + 2 * t]     = cy1;
        cf[40 + 2 * t + 1] = sy1;
    }

    // ---- load row (L0), sum of squares ----
    float re[16], im[16];
    const float* xr = x + ((size_t)n << 10) + (t << 4);
    float ss = 0.f;
    #pragma unroll
    for (int r = 0; r < 16; r += 4) {
        const float4 v = *reinterpret_cast<const float4*>(xr + r);
        re[r] = v.x; re[r + 1] = v.y; re[r + 2] = v.z; re[r + 3] = v.w;
        ss += v.x * v.x + v.y * v.y + v.z * v.z + v.w * v.w;
    }
    #pragma unroll
    for (int b = 32; b > 0; b >>= 1) ss += __shfl_xor(ss, b, 64);
    const float scale = 1.0f / fmaxf(sqrtf(ss), 1e-12f);

    __syncthreads();   // cf[] ready

    // ========= layer 1, phase A (L0 local bits 0-3 -> wires 9,8,7,6) =========
    {   // wire 9 (SH=0): input is real, fold in normalization
        const float ar = cf[36], ai = cf[37], br = cf[38], bi = cf[39];
        #pragma unroll
        for (int r = 0; r < 16; r += 2) {
            const float v0 = re[r] * scale, v1 = re[r + 1] * scale;
            re[r]     =  ar * v0 + br * v1;  im[r]     = ai * v0 + bi * v1;
            re[r + 1] = -br * v0 + ar * v1;  im[r + 1] = bi * v0 - ai * v1;
        }
    }
    cg<1>(re, im, cf[32], cf[33], cf[34], cf[35]);   // wire 8
    cg<2>(re, im, cf[28], cf[29], cf[30], cf[31]);   // wire 7
    cg<3>(re, im, cf[24], cf[25], cf[26], cf[27]);   // wire 6

    // T1: L0 -> L1
    #pragma unroll
    for (int r = 0; r < 16; r += 4) {
        const int p = PF((t << 4) + r);
        *reinterpret_cast<float4*>(&reb[p]) = make_float4(re[r], re[r+1], re[r+2], re[r+3]);
        *reinterpret_cast<float4*>(&imb[p]) = make_float4(im[r], im[r+1], im[r+2], im[r+3]);
    }
    __syncthreads();
    {
        const int b0 = ((t >> 4) << 8) | (t & 15);
        #pragma unroll
        for (int r = 0; r < 16; ++r) {
            const int p = PF(b0 + (r << 4));
            re[r] = reb[p]; im[r] = imb[p];
        }
    }

    // ========= layer 1, phase B (L1 local bits 4-7 -> wires 5,4,3,2) =========
    cg<0>(re, im, cf[20], cf[21], cf[22], cf[23]);   // wire 5
    cg<1>(re, im, cf[16], cf[17], cf[18], cf[19]);   // wire 4
    cg<2>(re, im, cf[12], cf[13], cf[14], cf[15]);   // wire 3
    cg<3>(re, im, cf[ 8], cf[ 9], cf[10], cf[11]);   // wire 2

    // T2: L1 -> L2
    {
        const int b0 = ((t >> 4) << 8) | (t & 15);
        #pragma unroll
        for (int r = 0; r < 16; ++r) {
            const int p = PF(b0 + (r << 4));
            reb[p] = re[r]; imb[p] = im[r];
        }
    }
    __syncthreads();
    #pragma unroll
    for (int r = 0; r < 16; r += 4) {
        const int p = PF(((r >> 2) << 8) | (t << 2));
        float4 q = *reinterpret_cast<const float4*>(&reb[p]);
        re[r] = q.x; re[r+1] = q.y; re[r+2] = q.z; re[r+3] = q.w;
        q = *reinterpret_cast<const float4*>(&imb[p]);
        im[r] = q.x; im[r+1] = q.y; im[r+2] = q.z; im[r+3] = q.w;
    }

    // ========= layer 1, phase C (L2: i8=r2 -> wire 1, i9=r3 -> wire 0) =======
    cg<2>(re, im, cf[4], cf[5], cf[6], cf[7]);       // wire 1
    cg<3>(re, im, cf[0], cf[1], cf[2], cf[3]);       // wire 0

    // T3: L2 -> CNOT-ring gather -> L0
    #pragma unroll
    for (int r = 0; r < 16; r += 4) {
        const int p = PF(((r >> 2) << 8) | (t << 2));
        *reinterpret_cast<float4*>(&reb[p]) = make_float4(re[r], re[r+1], re[r+2], re[r+3]);
        *reinterpret_cast<float4*>(&imb[p]) = make_float4(im[r], im[r+1], im[r+2], im[r+3]);
    }
    __syncthreads();
    {
        const int gt = gperm(t << 4);
        #pragma unroll
        for (int r = 0; r < 16; ++r) {
            const int p = PF(gt ^ gperm(r));   // gperm(r) const-folds
            re[r] = reb[p]; im[r] = imb[p];
        }
    }

    // ========= layer 2, phase A2 (L0 -> wires 9,8,7,6) =========
    rg<0>(re, im, cf[58], cf[59]);   // wire 9
    rg<1>(re, im, cf[56], cf[57]);   // wire 8
    rg<2>(re, im, cf[54], cf[55]);   // wire 7
    rg<3>(re, im, cf[52], cf[53]);   // wire 6

    // T4: L0 -> L1 (same as T1)
    #pragma unroll
    for (int r = 0; r < 16; r += 4) {
        const int p = PF((t << 4) + r);
        *reinterpret_cast<float4*>(&reb[p]) = make_float4(re[r], re[r+1], re[r+2], re[r+3]);
        *reinterpret_cast<float4*>(&imb[p]) = make_float4(im[r], im[r+1], im[r+2], im[r+3]);
    }
    __syncthreads();
    {
        const int b0 = ((t >> 4) << 8) | (t & 15);
        #pragma unroll
        for (int r = 0; r < 16; ++r) {
            const int p = PF(b0 + (r << 4));
            re[r] = reb[p]; im[r] = imb[p];
        }
    }

    // ========= layer 2, phase B2 (L1 -> wires 5,4,3,2) =========
    rg<0>(re, im, cf[50], cf[51]);   // wire 5
    rg<1>(re, im, cf[48], cf[49]);   // wire 4
    rg<2>(re, im, cf[46], cf[47]);   // wire 3
    rg<3>(re, im, cf[44], cf[45]);   // wire 2

    // T5: L1 -> L2 (same as T2)
    {
        const int b0 = ((t >> 4) << 8) | (t & 15);
        #pragma unroll
        for (int r = 0; r < 16; ++r) {
            const int p = PF(b0 + (r << 4));
            reb[p] = re[r]; imb[p] = im[r];
        }
    }
    __syncthreads();
    #pragma unroll
    for (int r = 0; r < 16; r += 4) {
        const int p = PF(((r >> 2) << 8) | (t << 2));
        float4 q = *reinterpret_cast<const float4*>(&reb[p]);
        re[r] = q.x; re[r+1] = q.y; re[r+2] = q.z; re[r+3] = q.w;
        q = *reinterpret_cast<const float4*>(&imb[p]);
        im[r] = q.x; im[r+1] = q.y; im[r+2] = q.z; im[r+3] = q.w;
    }

    // ========= layer 2, phase C2 (L2 -> wires 1,0) =========
    rg<2>(re, im, cf[42], cf[43]);   // wire 1
    rg<3>(re, im, cf[40], cf[41]);   // wire 0

    // ---- Z expectations (L2 layout: i9i8=r3r2, i7..2=t, i1i0=r1r0) ----
    // wires 0,1,8,9 <- register bits (full reductions); wires 2..7 <- lane bits (WHT)
    float P = 0.f, a0 = 0.f, a1 = 0.f, a8 = 0.f, a9 = 0.f;
    #pragma unroll
    for (int r = 0; r < 16; ++r) {
        const float p = re[r] * re[r] + im[r] * im[r];
        P  += p;
        a0 += (r & 8) ? -p : p;   // wire 0 <- i bit 9 = r bit 3
        a1 += (r & 4) ? -p : p;   // wire 1 <- i bit 8 = r bit 2
        a8 += (r & 2) ? -p : p;   // wire 8 <- i bit 1 = r bit 1
        a9 += (r & 1) ? -p : p;   // wire 9 <- i bit 0 = r bit 0
    }
    #pragma unroll
    for (int b = 1; b < 64; b <<= 1) {
        a0 += __shfl_xor(a0, b, 64);
        a1 += __shfl_xor(a1, b, 64);
        a8 += __shfl_xor(a8, b, 64);
        a9 += __shfl_xor(a9, b, 64);
        const float e = __shfl_xor(P, b, 64);
        P = (t & b) ? (e - P) : (e + P);   // WHT: lane m -> sum_t (-1)^<m,t> P_t
    }
    float* o = out + (size_t)n * NW;
    if (t == 0) { o[0] = a0; o[1] = a1; o[8] = a8; o[9] = a9; }
    if (t == 32) o[2] = P;   // wire 2 <- i bit 7 = t bit 5
    if (t == 16) o[3] = P;   // wire 3 <- t bit 4
    if (t ==  8) o[4] = P;   // wire 4 <- t bit 3
    if (t ==  4) o[5] = P;   // wire 5 <- t bit 2
    if (t ==  2) o[6] = P;   // wire 6 <- t bit 1
    if (t ==  1) o[7] = P;   // wire 7 <- t bit 0
}

extern "C" void kernel_launch(void* const* d_in, const int* in_sizes, int n_in,
                              void* d_out, int out_size, void* d_ws, size_t ws_size,
                              hipStream_t stream) {
    const float* x   = (const float*)d_in[0];
    const float* rx0 = (const float*)d_in[1];
    const float* ry0 = (const float*)d_in[2];
    const float* ry1 = (const float*)d_in[3];
    float* out = (float*)d_out;
    const int nstates = in_sizes[0] >> 10;   // 4096
    qsa_main<<<nstates, 64, 0, stream>>>(x, rx0, ry0, ry1, out);
}

// Round 5
// 82.129 us; speedup vs baseline: 1.1399x; 1.0026x over previous
//
#include <hip/hip_runtime.h>

#define NW 10
typedef float f32x2 __attribute__((ext_vector_type(2)));

// CNOT-ring fused permutation: psi_final[i] = psi_in[gperm(i)].
// Linear over GF(2): gperm(a^b) = gperm(a)^gperm(b).
__device__ __forceinline__ int gperm(int v) {
    #pragma unroll
    for (int k = 9; k >= 0; --k) {
        const int cs = 9 - k;                 // control bit (qubit k)
        const int ts = 9 - ((k + 1) % NW);    // target bit (qubit (k+1)%10)
        v ^= ((v >> cs) & 1) << ts;
    }
    return v;
}

// Padded float2-element index: vector b128 sides at bank floor, scalar b64
// sides even-4-way (= b64 bandwidth floor). Parity-preserving (16B alignment).
__device__ __forceinline__ int PQ(int i) {
    return i + ((i >> 4) << 1) + ((i >> 8) << 1);
}
#define PBUF 1156   // PQ(1022)+2 = 1156 float2 = 9248 B

// readlane: broadcast lane value -> wave-uniform (SGPR)
__device__ __forceinline__ float rl(float v, int lane) {
    return __int_as_float(__builtin_amdgcn_readlane(__float_as_int(v), lane));
}

// ---- packed complex gate [[a,b],[-conj(b),conj(a)]], SH >= 1 ----
template<int SH>
__device__ __forceinline__ void cgp(float* re, float* im,
                                    float ar, float ai, float br, float bi) {
    #pragma unroll
    for (int base = 0; base < 16; base += (2 << SH)) {
        #pragma unroll
        for (int off = 0; off < (1 << SH); off += 2) {
            const int r0 = base + off, r1 = r0 + (1 << SH);
            const f32x2 v0r = {re[r0], re[r0+1]}, v0i = {im[r0], im[r0+1]};
            const f32x2 v1r = {re[r1], re[r1+1]}, v1i = {im[r1], im[r1+1]};
            const f32x2 n0r = ar*v0r - ai*v0i + br*v1r - bi*v1i;
            const f32x2 n0i = ar*v0i + ai*v0r + br*v1i + bi*v1r;
            const f32x2 n1r = ar*v1r + ai*v1i - br*v0r - bi*v0i;
            const f32x2 n1i = ar*v1i - ai*v1r - br*v0i + bi*v0r;
            re[r0]=n0r.x; re[r0+1]=n0r.y; im[r0]=n0i.x; im[r0+1]=n0i.y;
            re[r1]=n1r.x; re[r1+1]=n1r.y; im[r1]=n1i.x; im[r1+1]=n1i.y;
        }
    }
}

// scalar complex gate, SH = 0 (adjacent pairs)
__device__ __forceinline__ void cg0(float* re, float* im,
                                    float ar, float ai, float br, float bi) {
    #pragma unroll
    for (int r = 0; r < 16; r += 2) {
        const float v0r = re[r], v0i = im[r], v1r = re[r+1], v1i = im[r+1];
        re[r]   =  ar*v0r - ai*v0i + br*v1r - bi*v1i;
        im[r]   =  ar*v0i + ai*v0r + br*v1i + bi*v1r;
        re[r+1] = -br*v0r - bi*v0i + ar*v1r + ai*v1i;
        im[r+1] =  bi*v0r - br*v0i + ar*v1i - ai*v1r;
    }
}

// ---- packed real RY gate [[c,-s],[s,c]], SH >= 1 ----
template<int SH>
__device__ __forceinline__ void rgp(float* re, float* im, float c, float s) {
    #pragma unroll
    for (int base = 0; base < 16; base += (2 << SH)) {
        #pragma unroll
        for (int off = 0; off < (1 << SH); off += 2) {
            const int r0 = base + off, r1 = r0 + (1 << SH);
            const f32x2 v0r = {re[r0], re[r0+1]}, v0i = {im[r0], im[r0+1]};
            const f32x2 v1r = {re[r1], re[r1+1]}, v1i = {im[r1], im[r1+1]};
            const f32x2 n0r = c*v0r - s*v1r, n0i = c*v0i - s*v1i;
            const f32x2 n1r = s*v0r + c*v1r, n1i = s*v0i + c*v1i;
            re[r0]=n0r.x; re[r0+1]=n0r.y; im[r0]=n0i.x; im[r0+1]=n0i.y;
            re[r1]=n1r.x; re[r1+1]=n1r.y; im[r1]=n1i.x; im[r1+1]=n1i.y;
        }
    }
}

// scalar real RY gate, SH = 0
__device__ __forceinline__ void rg0(float* re, float* im, float c, float s) {
    #pragma unroll
    for (int r = 0; r < 16; r += 2) {
        const float v0r = re[r], v0i = im[r], v1r = re[r+1], v1i = im[r+1];
        re[r]   = c*v0r - s*v1r;  im[r]   = c*v0i - s*v1i;
        re[r+1] = s*v0r + c*v1r;  im[r+1] = s*v0i + c*v1i;
    }
}

// One wave (64 threads) per block = per state. 16 amps/lane.
// Layouts: L0: i = t<<4 | r;  L1: i = (t>>4)<<8 | r<<4 | (t&15);
//          L2: i = ((r>>2)&3)<<8 | t<<2 | (r&3).
__global__ __launch_bounds__(64) void qsa_main(
    const float* __restrict__ x,
    const float* __restrict__ rx0,
    const float* __restrict__ ry0,
    const float* __restrict__ ry1,
    float* __restrict__ out) {

    __shared__ __align__(16) float2 sp[PBUF];

    const int t = threadIdx.x;
    const int n = blockIdx.x;

    // ---- load row (L0 layout) ----
    float re[16], im[16];
    const float* xr = x + ((size_t)n << 10) + (t << 4);
    #pragma unroll
    for (int r = 0; r < 16; r += 4) {
        const float4 v = *reinterpret_cast<const float4*>(xr + r);
        re[r] = v.x; re[r+1] = v.y; re[r+2] = v.z; re[r+3] = v.w;
    }

    // ---- per-wire coefficients in lanes 0..9 (overlaps the x load) ----
    float car = 0.f, cai = 0.f, cbr = 0.f, cbi = 0.f, cc1 = 0.f, cs1 = 0.f;
    if (t < NW) {
        float sx, cx, sy0, cy0;
        sincosf(0.5f * rx0[t], &sx,  &cx);
        sincosf(0.5f * ry0[t], &sy0, &cy0);
        sincosf(0.5f * ry1[t], &cs1, &cc1);
        car =  cy0 * cx;  cai =  sy0 * sx;   // fused RY(ry0)*RX(rx0)
        cbr = -sy0 * cx;  cbi = -cy0 * sx;
    }

    // ---- sum of squares -> normalization ----
    float ss = 0.f;
    #pragma unroll
    for (int r = 0; r < 16; ++r) ss += re[r] * re[r];
    #pragma unroll
    for (int b = 32; b > 0; b >>= 1) ss += __shfl_xor(ss, b, 64);
    const float scale = 1.0f / fmaxf(sqrtf(ss), 1e-12f);

    // ========= layer 1, phase A (L0 bits 0-3 -> wires 9,8,7,6) =========
    {   // wire 9 (SH=0): input is real; fold in normalization. Packed over pairs.
        const float ar = rl(car,9), ai = rl(cai,9), br = rl(cbr,9), bi = rl(cbi,9);
        #pragma unroll
        for (int r = 0; r < 16; r += 4) {
            const f32x2 v0 = {re[r] * scale,   re[r+2] * scale};
            const f32x2 v1 = {re[r+1] * scale, re[r+3] * scale};
            const f32x2 n0r = ar*v0 + br*v1, n0i = ai*v0 + bi*v1;
            const f32x2 n1r = ar*v1 - br*v0, n1i = bi*v0 - ai*v1;
            re[r]   = n0r.x; im[r]   = n0i.x; re[r+1] = n1r.x; im[r+1] = n1i.x;
            re[r+2] = n0r.y; im[r+2] = n0i.y; re[r+3] = n1r.y; im[r+3] = n1i.y;
        }
    }
    cgp<1>(re, im, rl(car,8), rl(cai,8), rl(cbr,8), rl(cbi,8));   // wire 8
    cgp<2>(re, im, rl(car,7), rl(cai,7), rl(cbr,7), rl(cbi,7));   // wire 7
    cgp<3>(re, im, rl(car,6), rl(cai,6), rl(cbr,6), rl(cbi,6));   // wire 6

    // T1: write L0 (b128), read L1 (b64)
    #pragma unroll
    for (int r = 0; r < 16; r += 2)
        *reinterpret_cast<float4*>(&sp[PQ((t << 4) | r)]) =
            make_float4(re[r], im[r], re[r+1], im[r+1]);
    __syncthreads();
    {
        const int b0 = ((t >> 4) << 8) | (t & 15);
        #pragma unroll
        for (int r = 0; r < 16; ++r) {
            const float2 v = sp[PQ(b0 + (r << 4))];
            re[r] = v.x; im[r] = v.y;
        }
    }

    // ========= layer 1, phase B (L1 bits 4-7 -> wires 5,4,3,2) =========
    cg0   (re, im, rl(car,5), rl(cai,5), rl(cbr,5), rl(cbi,5));   // wire 5
    cgp<1>(re, im, rl(car,4), rl(cai,4), rl(cbr,4), rl(cbi,4));   // wire 4
    cgp<2>(re, im, rl(car,3), rl(cai,3), rl(cbr,3), rl(cbi,3));   // wire 3
    cgp<3>(re, im, rl(car,2), rl(cai,2), rl(cbr,2), rl(cbi,2));   // wire 2

    // T2: write L1 (b64, own slots), read L2 (b128)
    {
        const int b0 = ((t >> 4) << 8) | (t & 15);
        #pragma unroll
        for (int r = 0; r < 16; ++r)
            sp[PQ(b0 + (r << 4))] = make_float2(re[r], im[r]);
    }
    __syncthreads();
    #pragma unroll
    for (int r = 0; r < 16; r += 2) {
        const int i = ((r >> 2) << 8) | (t << 2) | (r & 3);
        const float4 q = *reinterpret_cast<const float4*>(&sp[PQ(i)]);
        re[r] = q.x; im[r] = q.y; re[r+1] = q.z; im[r+1] = q.w;
    }

    // ========= layer 1, phase C (L2: bit8=wire1, bit9=wire0) =========
    cgp<2>(re, im, rl(car,1), rl(cai,1), rl(cbr,1), rl(cbi,1));   // wire 1
    cgp<3>(re, im, rl(car,0), rl(cai,0), rl(cbr,0), rl(cbi,0));   // wire 0

    // T3: write L2 (b128, own slots), read CNOT-ring gather -> L0
    #pragma unroll
    for (int r = 0; r < 16; r += 2) {
        const int i = ((r >> 2) << 8) | (t << 2) | (r & 3);
        *reinterpret_cast<float4*>(&sp[PQ(i)]) =
            make_float4(re[r], im[r], re[r+1], im[r+1]);
    }
    __syncthreads();
    {
        const int gt = gperm(t << 4);
        #pragma unroll
        for (int r = 0; r < 16; ++r) {
            const float2 v = sp[PQ(gt ^ gperm(r))];   // gperm(r) const-folds
            re[r] = v.x; im[r] = v.y;
        }
    }

    // ========= layer 2, phase A2 (L0 -> wires 9,8,7,6) =========
    rg0   (re, im, rl(cc1,9), rl(cs1,9));   // wire 9
    rgp<1>(re, im, rl(cc1,8), rl(cs1,8));   // wire 8
    rgp<2>(re, im, rl(cc1,7), rl(cs1,7));   // wire 7
    rgp<3>(re, im, rl(cc1,6), rl(cs1,6));   // wire 6

    // T4: write L0 (b128), read L1 (b64)
    #pragma unroll
    for (int r = 0; r < 16; r += 2)
        *reinterpret_cast<float4*>(&sp[PQ((t << 4) | r)]) =
            make_float4(re[r], im[r], re[r+1], im[r+1]);
    __syncthreads();
    {
        const int b0 = ((t >> 4) << 8) | (t & 15);
        #pragma unroll
        for (int r = 0; r < 16; ++r) {
            const float2 v = sp[PQ(b0 + (r << 4))];
            re[r] = v.x; im[r] = v.y;
        }
    }

    // ========= layer 2, phase B2 (L1 -> wires 5,4,3,2) =========
    rg0   (re, im, rl(cc1,5), rl(cs1,5));   // wire 5
    rgp<1>(re, im, rl(cc1,4), rl(cs1,4));   // wire 4
    rgp<2>(re, im, rl(cc1,3), rl(cs1,3));   // wire 3
    rgp<3>(re, im, rl(cc1,2), rl(cs1,2));   // wire 2

    // T5: write L1 (b64, own slots), read L2 (b128)
    {
        const int b0 = ((t >> 4) << 8) | (t & 15);
        #pragma unroll
        for (int r = 0; r < 16; ++r)
            sp[PQ(b0 + (r << 4))] = make_float2(re[r], im[r]);
    }
    __syncthreads();
    #pragma unroll
    for (int r = 0; r < 16; r += 2) {
        const int i = ((r >> 2) << 8) | (t << 2) | (r & 3);
        const float4 q = *reinterpret_cast<const float4*>(&sp[PQ(i)]);
        re[r] = q.x; im[r] = q.y; re[r+1] = q.z; im[r+1] = q.w;
    }

    // ========= layer 2, phase C2 (L2 -> wires 1,0) =========
    rgp<2>(re, im, rl(cc1,1), rl(cs1,1));   // wire 1
    rgp<3>(re, im, rl(cc1,0), rl(cs1,0));   // wire 0

    // ---- Z expectations (L2: i9i8 = r3r2, i7..2 = t, i1i0 = r1r0) ----
    float P = 0.f, a0 = 0.f, a1 = 0.f, a8 = 0.f, a9 = 0.f;
    #pragma unroll
    for (int r = 0; r < 16; ++r) {
        const float p = re[r] * re[r] + im[r] * im[r];
        P  += p;
        a0 += (r & 8) ? -p : p;   // wire 0 <- i bit 9 = r bit 3
        a1 += (r & 4) ? -p : p;   // wire 1 <- i bit 8 = r bit 2
        a8 += (r & 2) ? -p : p;   // wire 8 <- i bit 1 = r bit 1
        a9 += (r & 1) ? -p : p;   // wire 9 <- i bit 0 = r bit 0
    }
    #pragma unroll
    for (int b = 1; b < 64; b <<= 1) {
        a0 += __shfl_xor(a0, b, 64);
        a1 += __shfl_xor(a1, b, 64);
        a8 += __shfl_xor(a8, b, 64);
        a9 += __shfl_xor(a9, b, 64);
        const float e = __shfl_xor(P, b, 64);
        P = (t & b) ? (e - P) : (e + P);   // WHT over lane bits
    }
    float* o = out + (size_t)n * NW;
    if (t == 0) { o[0] = a0; o[1] = a1; o[8] = a8; o[9] = a9; }
    if (t == 32) o[2] = P;   // wire 2 <- t bit 5
    if (t == 16) o[3] = P;   // wire 3 <- t bit 4
    if (t ==  8) o[4] = P;   // wire 4 <- t bit 3
    if (t ==  4) o[5] = P;   // wire 5 <- t bit 2
    if (t ==  2) o[6] = P;   // wire 6 <- t bit 1
    if (t ==  1) o[7] = P;   // wire 7 <- t bit 0
}

extern "C" void kernel_launch(void* const* d_in, const int* in_sizes, int n_in,
                              void* d_out, int out_size, void* d_ws, size_t ws_size,
                              hipStream_t stream) {
    const float* x   = (const float*)d_in[0];
    const float* rx0 = (const float*)d_in[1];
    const float* ry0 = (const float*)d_in[2];
    const float* ry1 = (const float*)d_in[3];
    float* out = (float*)d_out;
    const int nstates = in_sizes[0] >> 10;   // 4096
    qsa_main<<<nstates, 64, 0, stream>>>(x, rx0, ry0, ry1, out);
}